// Round 1
// baseline (164.024 us; speedup 1.0000x reference)
//
#include <hip/hip_runtime.h>
#include <stdint.h>

// DETR post-process: per batch n of 256, top-300 of sigmoid(logits[n]) (80000
// elems), output [label, score, scaled box] per selected query.
//
// Ordering: jax top_k = score desc, tie -> lowest index. sigmoid is strictly
// monotonic, so we select/sort on 64-bit key (ord(logit)<<32 | ~index):
// descending key order == (score desc, index asc) exactly. Sigmoid only
// computed for the 300 winners.

#define TOPK 300
#define NCLS 80
#define NQ 1000
#define QK (NQ * NCLS)   // 80000
#define NB 2048          // histogram bins (11 bits of ordered value)
#define CAP 2048         // candidate buffer (expected ~500 for normal data)
#define THREADS 1024

typedef unsigned long long u64;

__device__ __forceinline__ uint32_t ordf(float f) {
  uint32_t u = __float_as_uint(f);
  return (u & 0x80000000u) ? ~u : (u | 0x80000000u);  // monotonic float->uint
}
__device__ __forceinline__ float unordf(uint32_t o) {
  uint32_t u = (o & 0x80000000u) ? (o & 0x7fffffffu) : ~o;
  return __uint_as_float(u);
}

__global__ __launch_bounds__(THREADS) void detr_post_kernel(
    const float* __restrict__ logits, const float* __restrict__ boxes,
    const int* __restrict__ osz, float* __restrict__ out) {
  // LDS: 32K hist4 + 8K histf + 16K buf = ~56 KB (< 64 KB/workgroup)
  __shared__ uint32_t hist4[NB * 4];  // 4-way replicated (lane&3) to cut
                                      // same-address atomic serialization
  __shared__ uint32_t histf[NB];
  __shared__ u64 buf[CAP];
  __shared__ uint32_t sh_sel[3];  // {bin, suffix[bin+1], suffix[bin]}
  __shared__ uint32_t sh_cnt;

  const int n = blockIdx.x;
  const int t = threadIdx.x;
  const uint32_t sub = (uint32_t)(t & 3);
  const float* lg = logits + (size_t)n * QK;

  // ---- multi-level radix select on ord(logit): find threshold T such that
  // count(ord >= T) is in [300, CAP]. Level 0 (bits 31:21) almost always
  // suffices for normal-distributed logits (~500 candidates).
  uint32_t T = 0;       // selected ord prefix, low bits zero
  uint32_t S_above = 0; // global count strictly above current bin path
  uint32_t Krem = TOPK;
  int prev_shift = 32;
  uint32_t cand_global = 0;

  const int shifts[3] = {21, 10, 0};
  const int nbns[3] = {2048, 2048, 1024};

  for (int lvl = 0; lvl < 3; ++lvl) {
    const int sh = shifts[lvl];
    const uint32_t nb = (uint32_t)nbns[lvl];

    for (int b = t; b < NB * 4; b += THREADS) hist4[b] = 0;
    __syncthreads();

    for (int i = 4 * t; i < QK; i += 4 * THREADS) {
      const float4 v = *(const float4*)(lg + i);
      const float vs[4] = {v.x, v.y, v.z, v.w};
#pragma unroll
      for (int c = 0; c < 4; ++c) {
        uint32_t u = ordf(vs[c]);
        if (lvl == 0 || (u >> prev_shift) == (T >> prev_shift))
          atomicAdd(&hist4[(((u >> sh) & (nb - 1)) << 2) | sub], 1u);
      }
    }
    __syncthreads();

    // fold the 4 replicas
    for (uint32_t b = t; b < nb; b += (uint32_t)THREADS) {
      uint32_t i4 = b << 2;
      histf[b] = hist4[i4] + hist4[i4 + 1] + hist4[i4 + 2] + hist4[i4 + 3];
    }
    __syncthreads();

    // inclusive suffix sum: histf[b] = count(bin >= b)
    for (uint32_t off = 1; off < nb; off <<= 1) {
      uint32_t a0 = histf[t] + ((t + off < nb) ? histf[t + off] : 0u);
      uint32_t a1 = 0;
      if (nb > (uint32_t)THREADS) {
        uint32_t i1 = (uint32_t)t + THREADS;
        a1 = histf[i1] + ((i1 + off < nb) ? histf[i1 + off] : 0u);
      }
      __syncthreads();
      histf[t] = a0;
      if (nb > (uint32_t)THREADS) histf[(uint32_t)t + THREADS] = a1;
      __syncthreads();
    }

    // threshold bin: suffix[b] >= Krem, suffix[b+1] < Krem (unique, monotone)
    for (uint32_t b = t; b < nb; b += (uint32_t)THREADS) {
      uint32_t s = histf[b];
      uint32_t sn = (b + 1 < nb) ? histf[b + 1] : 0u;
      if (s >= Krem && sn < Krem) {
        sh_sel[0] = b;
        sh_sel[1] = sn;
        sh_sel[2] = s;
      }
    }
    __syncthreads();
    const uint32_t bsel = sh_sel[0], above = sh_sel[1], candL = sh_sel[2];
    __syncthreads();  // sh_sel/histf consumed before next level overwrites

    T |= bsel << sh;
    cand_global = S_above + candL;
    if (cand_global <= CAP || lvl == 2) break;
    S_above += above;
    Krem -= above;
    prev_shift = sh;
  }

  // ---- compact candidates (ord >= T) into LDS as 64-bit keys
  if (t == 0) sh_cnt = 0;
  __syncthreads();
  for (int i = 4 * t; i < QK; i += 4 * THREADS) {
    const float4 v = *(const float4*)(lg + i);
    const float vs[4] = {v.x, v.y, v.z, v.w};
#pragma unroll
    for (int c = 0; c < 4; ++c) {
      uint32_t u = ordf(vs[c]);
      if (u >= T) {
        uint32_t p = atomicAdd(&sh_cnt, 1u);
        if (p < CAP)  // clamp only reachable for adversarial mass-tie inputs
          buf[p] = ((u64)u << 32) | (u64)(uint32_t)(~(uint32_t)(i + c));
      }
    }
  }
  __syncthreads();
  const uint32_t cnt = sh_cnt < CAP ? sh_cnt : CAP;
  for (uint32_t p = t; p < CAP; p += (uint32_t)THREADS)
    if (p >= cnt) buf[p] = 0ULL;  // pad sorts last (real keys have high bits)
  __syncthreads();

  // ---- bitonic sort CAP keys, descending
  for (int k = 2; k <= CAP; k <<= 1) {
    for (int j = k >> 1; j > 0; j >>= 1) {
      for (int i = t; i < CAP; i += THREADS) {
        int l = i ^ j;
        if (l > i) {
          u64 a = buf[i], b = buf[l];
          bool desc = ((i & k) == 0);
          if (desc ? (a < b) : (a > b)) {
            buf[i] = b;
            buf[l] = a;
          }
        }
      }
      __syncthreads();
    }
  }

  // ---- epilogue: decode top-300 rows
  if (t < TOPK) {
    const u64 key = buf[t];
    const uint32_t u = (uint32_t)(key >> 32);
    const uint32_t idx = ~(uint32_t)(key & 0xffffffffu);
    const float lgv = unordf(u);
    const float score = 1.0f / (1.0f + expf(-lgv));
    const uint32_t q = idx / NCLS;
    const uint32_t lab = idx - q * NCLS;
    const float* bp = boxes + ((size_t)n * NQ + q) * 4;
    const float cx = bp[0], cy = bp[1], w = bp[2], h = bp[3];
    // sizes_wh = tile(original_sizes[0][::-1], 2) = [v1, v0, v1, v0]
    const float s0 = (float)osz[0];
    const float s1 = (float)osz[1];
    float* op = out + ((size_t)n * TOPK + t) * 6;
    op[0] = (float)lab;
    op[1] = score;
    op[2] = (cx - 0.5f * w) * s1;
    op[3] = (cy - 0.5f * h) * s0;
    op[4] = w * s1;
    op[5] = h * s0;
  }
}

extern "C" void kernel_launch(void* const* d_in, const int* in_sizes, int n_in,
                              void* d_out, int out_size, void* d_ws, size_t ws_size,
                              hipStream_t stream) {
  const float* logits = (const float*)d_in[0];
  const float* boxes = (const float*)d_in[1];
  const int* osz = (const int*)d_in[2];
  float* out = (float*)d_out;
  const int nbatch = in_sizes[0] / QK;  // 256
  detr_post_kernel<<<nbatch, THREADS, 0, stream>>>(logits, boxes, osz, out);
}

// Round 2
// 159.218 us; speedup vs baseline: 1.0302x; 1.0302x over previous
//
#include <hip/hip_runtime.h>
#include <stdint.h>

// DETR post-process: per batch n of 256, top-300 of sigmoid(logits[n]) (80000
// elems), output [label, score, scaled box] per selected query.
//
// Ordering: jax top_k = score desc, tie -> lowest index. sigmoid is strictly
// monotonic, so we select/rank on 64-bit key (ord(logit)<<32 | ~index):
// descending key order == (score desc, index asc) exactly.
//
// R2 structure: one 1024-thread block per batch.
//   1. load logits once, keep ordered-uint values in REGISTERS (80/thread)
//      while building a 2048-bin LDS histogram of the top-11 ordered bits.
//   2. radix-select threshold T (refinement levels re-read registers, not
//      global) so that count(ord >= T) is in [300, 2048]  (~500 typical).
//   3. compact candidates (from registers) into LDS as u64 keys.
//   4. rank-by-count (LDS broadcast reads, no sort, no 66-stage bitonic):
//      rank = #keys greater; rank<300 writes its output row directly.

#define TOPK 300
#define NCLS 80
#define NQ 1000
#define QK (NQ * NCLS)   // 80000
#define NB 2048          // histogram bins (11 bits)
#define CAP 2048         // candidate buffer
#define THREADS 1024
#define ITERS 20         // ceil(QK / (4*THREADS)); last iter valid iff t<544
#define LAST_VALID 544   // 4*t + 4096*19 < 80000  <=>  t < 544

typedef unsigned long long u64;

__device__ __forceinline__ uint32_t ordf(float f) {
  uint32_t u = __float_as_uint(f);
  return (u & 0x80000000u) ? ~u : (u | 0x80000000u);  // monotonic float->uint
}
__device__ __forceinline__ float unordf(uint32_t o) {
  uint32_t u = (o & 0x80000000u) ? (o & 0x7fffffffu) : ~o;
  return __uint_as_float(u);
}

__global__ __launch_bounds__(THREADS) void detr_post_kernel(
    const float* __restrict__ logits, const float* __restrict__ boxes,
    const int* __restrict__ osz, float* __restrict__ out) {
  __shared__ uint32_t hist4[NB * 4];  // 4-way replicated (t&3) histogram
  __shared__ uint32_t histf[NB];
  __shared__ u64 buf[CAP];
  __shared__ uint32_t sh_sel[3];  // {bin, suffix[bin+1], suffix[bin]}
  __shared__ uint32_t sh_cnt;

  const int n = blockIdx.x;
  const int t = threadIdx.x;
  const uint32_t sub = (uint32_t)(t & 3);
  const float* lg = logits + (size_t)n * QK;

  // ---- phase 1: load into registers + level-0 histogram
  uint32_t vals[ITERS * 4];

  for (int b = t; b < NB * 4; b += THREADS) hist4[b] = 0;
  __syncthreads();

#pragma unroll
  for (int j = 0; j < ITERS; ++j) {
    const int i = 4 * t + 4096 * j;
    if (j < ITERS - 1 || t < LAST_VALID) {
      const float4 v = *(const float4*)(lg + i);
      vals[4 * j + 0] = ordf(v.x);
      vals[4 * j + 1] = ordf(v.y);
      vals[4 * j + 2] = ordf(v.z);
      vals[4 * j + 3] = ordf(v.w);
#pragma unroll
      for (int c = 0; c < 4; ++c)
        atomicAdd(&hist4[(((vals[4 * j + c] >> 21) & (NB - 1)) << 2) | sub], 1u);
    } else {
      vals[4 * j + 0] = vals[4 * j + 1] = vals[4 * j + 2] = vals[4 * j + 3] = 0;
    }
  }

  // ---- phase 2: radix select (level 0 from the histogram we just built;
  // refinement levels 1/2 rebuild from registers — no global traffic)
  uint32_t T = 0;
  uint32_t S_above = 0;
  uint32_t Krem = TOPK;
  int prev_shift = 32;

  const int shifts[3] = {21, 10, 0};
  const int nbns[3] = {2048, 2048, 1024};

  for (int lvl = 0; lvl < 3; ++lvl) {
    const int sh = shifts[lvl];
    const uint32_t nb = (uint32_t)nbns[lvl];

    if (lvl > 0) {
      for (int b = t; b < NB * 4; b += THREADS) hist4[b] = 0;
      __syncthreads();
#pragma unroll
      for (int j = 0; j < ITERS; ++j) {
        if (j == ITERS - 1 && t >= LAST_VALID) break;
#pragma unroll
        for (int c = 0; c < 4; ++c) {
          const uint32_t u = vals[4 * j + c];
          if ((u >> prev_shift) == (T >> prev_shift))
            atomicAdd(&hist4[(((u >> sh) & (nb - 1)) << 2) | sub], 1u);
        }
      }
    }
    __syncthreads();

    // fold the 4 replicas
    for (uint32_t b = t; b < nb; b += (uint32_t)THREADS) {
      const uint32_t i4 = b << 2;
      histf[b] = hist4[i4] + hist4[i4 + 1] + hist4[i4 + 2] + hist4[i4 + 3];
    }
    __syncthreads();

    // inclusive suffix sum: histf[b] = count(bin >= b)
    for (uint32_t off = 1; off < nb; off <<= 1) {
      uint32_t a0 = histf[t] + ((t + off < nb) ? histf[t + off] : 0u);
      uint32_t a1 = 0;
      if (nb > (uint32_t)THREADS) {
        const uint32_t i1 = (uint32_t)t + THREADS;
        a1 = histf[i1] + ((i1 + off < nb) ? histf[i1 + off] : 0u);
      }
      __syncthreads();
      histf[t] = a0;
      if (nb > (uint32_t)THREADS) histf[(uint32_t)t + THREADS] = a1;
      __syncthreads();
    }

    // threshold bin: suffix[b] >= Krem, suffix[b+1] < Krem (unique, monotone)
    for (uint32_t b = t; b < nb; b += (uint32_t)THREADS) {
      const uint32_t s = histf[b];
      const uint32_t sn = (b + 1 < nb) ? histf[b + 1] : 0u;
      if (s >= Krem && sn < Krem) {
        sh_sel[0] = b;
        sh_sel[1] = sn;
        sh_sel[2] = s;
      }
    }
    __syncthreads();
    const uint32_t bsel = sh_sel[0], above = sh_sel[1], candL = sh_sel[2];
    __syncthreads();  // sh_sel consumed before any next-level overwrite

    T |= bsel << sh;
    if (S_above + candL <= CAP || lvl == 2) break;
    S_above += above;
    Krem -= above;
    prev_shift = sh;
  }

  // ---- phase 3: compact candidates (ord >= T) from registers into LDS
  if (t == 0) sh_cnt = 0;
  __syncthreads();
#pragma unroll
  for (int j = 0; j < ITERS; ++j) {
    if (j == ITERS - 1 && t >= LAST_VALID) break;
#pragma unroll
    for (int c = 0; c < 4; ++c) {
      const uint32_t u = vals[4 * j + c];
      if (u >= T) {
        const uint32_t p = atomicAdd(&sh_cnt, 1u);
        const uint32_t idx = (uint32_t)(4 * t + 4096 * j + c);
        if (p < CAP)  // clamp only reachable for adversarial mass-tie inputs
          buf[p] = ((u64)u << 32) | (u64)(~idx);
      }
    }
  }
  __syncthreads();
  const uint32_t cnt = sh_cnt < CAP ? sh_cnt : CAP;
  const uint32_t cnt4 = (cnt + 3u) & ~3u;
  for (uint32_t p = cnt + t; p < cnt4; p += (uint32_t)THREADS)
    buf[p] = 0ULL;  // pad for 4-wide rank loop; 0 < any real key
  __syncthreads();

  // ---- phase 4: rank by counting (LDS broadcast: all threads read the same
  // buf[q] each iteration -> conflict-free), then direct scatter to output
  const float s0 = (float)osz[0];
  const float s1 = (float)osz[1];
  for (uint32_t p = t; p < cnt; p += (uint32_t)THREADS) {
    const u64 my = buf[p];
    uint32_t rank = 0;
    for (uint32_t q = 0; q < cnt4; q += 4) {
      const u64 k0 = buf[q + 0], k1 = buf[q + 1];
      const u64 k2 = buf[q + 2], k3 = buf[q + 3];
      rank += (uint32_t)(k0 > my) + (uint32_t)(k1 > my) +
              (uint32_t)(k2 > my) + (uint32_t)(k3 > my);
    }
    if (rank < TOPK) {
      const uint32_t u = (uint32_t)(my >> 32);
      const uint32_t idx = ~(uint32_t)(my & 0xffffffffu);
      const float lgv = unordf(u);
      const float score = 1.0f / (1.0f + expf(-lgv));
      const uint32_t q = idx / NCLS;
      const uint32_t lab = idx - q * NCLS;
      const float* bp = boxes + ((size_t)n * NQ + q) * 4;
      const float cx = bp[0], cy = bp[1], w = bp[2], h = bp[3];
      float* op = out + ((size_t)n * TOPK + rank) * 6;
      op[0] = (float)lab;
      op[1] = score;
      op[2] = (cx - 0.5f * w) * s1;
      op[3] = (cy - 0.5f * h) * s0;
      op[4] = w * s1;
      op[5] = h * s0;
    }
  }
}

extern "C" void kernel_launch(void* const* d_in, const int* in_sizes, int n_in,
                              void* d_out, int out_size, void* d_ws, size_t ws_size,
                              hipStream_t stream) {
  const float* logits = (const float*)d_in[0];
  const float* boxes = (const float*)d_in[1];
  const int* osz = (const int*)d_in[2];
  float* out = (float*)d_out;
  const int nbatch = in_sizes[0] / QK;  // 256
  detr_post_kernel<<<nbatch, THREADS, 0, stream>>>(logits, boxes, osz, out);
}